// Round 3
// baseline (1597.863 us; speedup 1.0000x reference)
//
#include <hip/hip_runtime.h>
#include <stdint.h>

#define NB 8
#define NN 4096
#define NP 1024
#define NSAMP 32
#define CIN 64
#define C0IN 67
#define C3 128

// ---- Kernel 1: farthest point sampling; also writes new_xyz directly ------
__global__ __launch_bounds__(256) void fps_kernel(
    const float* __restrict__ xyz, unsigned short* __restrict__ fps_idx,
    float* __restrict__ out_xyz) {
#pragma clang fp contract(off)
  __shared__ float sx[NN], sy[NN], sz[NN];
  __shared__ float wbest[4];
  __shared__ int wbi[4];
  __shared__ int scur;
  const int b = blockIdx.x;
  const int tid = threadIdx.x;
  const float* xb = xyz + (size_t)b * NN * 3;
  for (int i = tid; i < NN; i += 256) {
    sx[i] = xb[3 * i + 0];
    sy[i] = xb[3 * i + 1];
    sz[i] = xb[3 * i + 2];
  }
  if (tid == 0) {
    scur = 0;
    fps_idx[b * NP] = 0;
    out_xyz[(size_t)b * NP * 3 + 0] = xb[0];
    out_xyz[(size_t)b * NP * 3 + 1] = xb[1];
    out_xyz[(size_t)b * NP * 3 + 2] = xb[2];
  }
  __syncthreads();
  float px[16], py[16], pz[16], dist[16];
#pragma unroll
  for (int j = 0; j < 16; ++j) {
    int i = (j << 8) + tid;
    px[j] = sx[i]; py[j] = sy[i]; pz[j] = sz[i];
    dist[j] = 1e10f;
  }
  const int wid = tid >> 6;
  const int lane = tid & 63;
  for (int k = 1; k < NP; ++k) {
    const int cur = scur;  // written by tid0 last iter, barrier-protected
    const float qx = sx[cur], qy = sy[cur], qz = sz[cur];
    float best = -1.0f;
    int bi = 0;
#pragma unroll
    for (int j = 0; j < 16; ++j) {
      float dx = px[j] - qx;
      float dy = py[j] - qy;
      float dz = pz[j] - qz;
      float d = dx * dx + dy * dy + dz * dz;  // contract off: np order ((x+y)+z)
      float nd = fminf(dist[j], d);
      dist[j] = nd;
      int idx = (j << 8) + tid;
      if (nd > best) { best = nd; bi = idx; }
    }
#pragma unroll
    for (int off = 32; off > 0; off >>= 1) {
      float ob = __shfl_xor(best, off, 64);
      int oi = __shfl_xor(bi, off, 64);
      if ((ob > best) || (ob == best && oi < bi)) { best = ob; bi = oi; }
    }
    if (lane == 0) { wbest[wid] = best; wbi[wid] = bi; }
    __syncthreads();
    if (tid == 0) {
      float bb = wbest[0];
      int ii = wbi[0];
#pragma unroll
      for (int w = 1; w < 4; ++w) {
        float wd = wbest[w];
        int wi = wbi[w];
        if ((wd > bb) || (wd == bb && wi < ii)) { bb = wd; ii = wi; }
      }
      scur = ii;
      fps_idx[b * NP + k] = (unsigned short)ii;
      out_xyz[((size_t)b * NP + k) * 3 + 0] = xb[3 * ii + 0];
      out_xyz[((size_t)b * NP + k) * 3 + 1] = xb[3 * ii + 1];
      out_xyz[((size_t)b * NP + k) * 3 + 2] = xb[3 * ii + 2];
    }
    __syncthreads();
  }
}

// ---- Kernel 2: ball query (one wave per center) ---------------------------
__global__ __launch_bounds__(256) void ballq_kernel(
    const float* __restrict__ xyz, const unsigned short* __restrict__ fps_idx,
    unsigned short* __restrict__ gidx) {
#pragma clang fp contract(off)
  const int tid = threadIdx.x;
  const int gid = blockIdx.x * 4 + (tid >> 6);  // center id 0..8191
  const int lane = tid & 63;
  const int b = gid >> 10;
  const int s = gid & 1023;
  const float* xb = xyz + (size_t)b * NN * 3;
  const int ci = (int)fps_idx[b * NP + s] & (NN - 1);
  const float cx = xb[ci * 3 + 0];
  const float cy = xb[ci * 3 + 1];
  const float cz = xb[ci * 3 + 2];
  const float nn = (cx * cx + cy * cy) + cz * cz;  // ref order
  const float r2 = 0.04f;
  unsigned short* gout = gidx + (size_t)(b * NP + s) * NSAMP;
  int total = 0;
  int first = -1;
  for (int c = 0; c < NN / 64 && total < NSAMP; ++c) {
    int i = (c << 6) + lane;
    float x = xb[i * 3 + 0];
    float y = xb[i * 3 + 1];
    float z = xb[i * 3 + 2];
    float pp = (x * x + y * y) + z * z;
    float dt = (x * cx + y * cy) + z * cz;
    float sq = (nn + pp) - 2.0f * dt;  // exact ref formula; self-dist == 0
    bool inb = !(sq > r2);
    unsigned long long m = __ballot(inb);
    if (first < 0 && m) first = (c << 6) + (__ffsll((unsigned long long)m) - 1);
    int before = __popcll(m & ((1ull << lane) - 1ull));
    int slot = total + before;
    if (inb && slot < NSAMP) gout[slot] = (unsigned short)i;
    total += (int)__popcll(m);
  }
  int cnt = total < NSAMP ? total : NSAMP;
  unsigned short fill = (unsigned short)(first < 0 ? 0 : first);
  if (lane >= cnt && lane < NSAMP) gout[lane] = fill;
}

// ---- Kernel 3: gather + MLP(67->64->64->128) + max ------------------------
// LDS plan (static, < 64 KB):
//   wbuf[8192]  : one layer's weights at a time (W2 is 64*128 = 8192 floats)
//   xbuf[4256]  : xs(j,k)=xbuf[j*68+k] (input / h1), h0(j,c)=xbuf[2176+j*65+c],
//                 hb2(j,c)=xbuf[j*132+c] overlays xs+h0 after they're dead
//   prm[768]    : bias/gamma*bnsc/beta for all 3 layers
__global__ __launch_bounds__(256) void mlp_kernel(
    const float* __restrict__ xyz, const float* __restrict__ points,
    const unsigned short* __restrict__ fps_idx, const unsigned short* __restrict__ gidx,
    const float* __restrict__ W0, const float* __restrict__ b0,
    const float* __restrict__ g0, const float* __restrict__ be0,
    const float* __restrict__ W1, const float* __restrict__ b1,
    const float* __restrict__ g1, const float* __restrict__ be1,
    const float* __restrict__ W2, const float* __restrict__ b2,
    const float* __restrict__ g2, const float* __restrict__ be2,
    float* __restrict__ out_feat) {
  __shared__ __align__(16) float wbuf[8192];
  __shared__ __align__(16) float xbuf[4256];
  __shared__ float prm[768];
  const int tid = threadIdx.x;
  const int b = blockIdx.x >> 10;
  const int s = blockIdx.x & 1023;
  const float bnsc = 1.0f / sqrtf(1.001f);
  const int j = tid >> 3;   // sample row 0..31
  const int cg = tid & 7;   // column group 0..7

  // stage W0 (67*64 = 4288 floats)
  for (int i = tid; i < C0IN * 64; i += 256) wbuf[i] = W0[i];
  if (tid < 64) {
    prm[tid] = b0[tid];       prm[64 + tid] = g0[tid] * bnsc;  prm[128 + tid] = be0[tid];
    prm[192 + tid] = b1[tid]; prm[256 + tid] = g1[tid] * bnsc; prm[320 + tid] = be1[tid];
  }
  if (tid < 128) {
    prm[384 + tid] = b2[tid]; prm[512 + tid] = g2[tid] * bnsc; prm[640 + tid] = be2[tid];
  }
  // gather: row j, 8 threads per row, 8 channels each
  const int idx = (int)gidx[(size_t)(b * NP + s) * NSAMP + j] & (NN - 1);
  {
    const float* pf = points + ((size_t)b * NN + idx) * CIN + cg * 8;
    const float4 v0 = *(const float4*)pf;
    const float4 v1 = *(const float4*)(pf + 4);
    float* xr = &xbuf[j * 68 + 3 + cg * 8];
    xr[0] = v0.x; xr[1] = v0.y; xr[2] = v0.z; xr[3] = v0.w;
    xr[4] = v1.x; xr[5] = v1.y; xr[6] = v1.z; xr[7] = v1.w;
    if (cg == 0) {
      const int ci = (int)fps_idx[b * NP + s] & (NN - 1);
      const float* xbp = xyz + (size_t)b * NN * 3;
      xbuf[j * 68 + 0] = xbp[idx * 3 + 0] - xbp[ci * 3 + 0];
      xbuf[j * 68 + 1] = xbp[idx * 3 + 1] - xbp[ci * 3 + 1];
      xbuf[j * 68 + 2] = xbp[idx * 3 + 2] - xbp[ci * 3 + 2];
    }
  }
  __syncthreads();
  // layer 0: 67 -> 64, this thread does cols cg*8 .. cg*8+7
  float accA[8];
#pragma unroll
  for (int m = 0; m < 8; ++m) accA[m] = 0.f;
  for (int k = 0; k < C0IN; ++k) {
    float xv = xbuf[j * 68 + k];
    float4 wa = *(const float4*)&wbuf[k * 64 + cg * 8];
    float4 wb = *(const float4*)&wbuf[k * 64 + cg * 8 + 4];
    accA[0] = fmaf(xv, wa.x, accA[0]);
    accA[1] = fmaf(xv, wa.y, accA[1]);
    accA[2] = fmaf(xv, wa.z, accA[2]);
    accA[3] = fmaf(xv, wa.w, accA[3]);
    accA[4] = fmaf(xv, wb.x, accA[4]);
    accA[5] = fmaf(xv, wb.y, accA[5]);
    accA[6] = fmaf(xv, wb.z, accA[6]);
    accA[7] = fmaf(xv, wb.w, accA[7]);
  }
#pragma unroll
  for (int m = 0; m < 8; ++m) {
    int c = cg * 8 + m;
    float z = accA[m] + prm[c];
    z = z > 0.f ? z : 0.f;
    xbuf[2176 + j * 65 + c] = z * prm[64 + c] + prm[128 + c];
  }
  __syncthreads();           // h0 ready; everyone done reading W0
  // stage W1 (64*64 = 4096 floats)
  for (int i = tid; i < 64 * 64; i += 256) wbuf[i] = W1[i];
  __syncthreads();
  // layer 1: 64 -> 64 (reads h0, writes h1 back into xs slots)
#pragma unroll
  for (int m = 0; m < 8; ++m) accA[m] = 0.f;
  for (int k = 0; k < 64; ++k) {
    float xv = xbuf[2176 + j * 65 + k];
    float4 wa = *(const float4*)&wbuf[k * 64 + cg * 8];
    float4 wb = *(const float4*)&wbuf[k * 64 + cg * 8 + 4];
    accA[0] = fmaf(xv, wa.x, accA[0]);
    accA[1] = fmaf(xv, wa.y, accA[1]);
    accA[2] = fmaf(xv, wa.z, accA[2]);
    accA[3] = fmaf(xv, wa.w, accA[3]);
    accA[4] = fmaf(xv, wb.x, accA[4]);
    accA[5] = fmaf(xv, wb.y, accA[5]);
    accA[6] = fmaf(xv, wb.z, accA[6]);
    accA[7] = fmaf(xv, wb.w, accA[7]);
  }
  __syncthreads();           // done reading W1 & h0 (h0 region stays, xs gets h1)
#pragma unroll
  for (int m = 0; m < 8; ++m) {
    int c = cg * 8 + m;
    float z = accA[m] + prm[192 + c];
    z = z > 0.f ? z : 0.f;
    xbuf[j * 68 + c] = z * prm[256 + c] + prm[320 + c];
  }
  // stage W2 (64*128 = 8192 floats)
  for (int i = tid; i < 64 * 128; i += 256) wbuf[i] = W2[i];
  __syncthreads();
  // layer 2: 64 -> 128, this thread does cols cg*16 .. cg*16+15
  float acc[16];
#pragma unroll
  for (int m = 0; m < 16; ++m) acc[m] = 0.f;
  for (int k = 0; k < 64; ++k) {
    float xv = xbuf[j * 68 + k];
    float4 wa = *(const float4*)&wbuf[k * 128 + cg * 16];
    float4 wb = *(const float4*)&wbuf[k * 128 + cg * 16 + 4];
    float4 wc = *(const float4*)&wbuf[k * 128 + cg * 16 + 8];
    float4 wd = *(const float4*)&wbuf[k * 128 + cg * 16 + 12];
    acc[0]  = fmaf(xv, wa.x, acc[0]);
    acc[1]  = fmaf(xv, wa.y, acc[1]);
    acc[2]  = fmaf(xv, wa.z, acc[2]);
    acc[3]  = fmaf(xv, wa.w, acc[3]);
    acc[4]  = fmaf(xv, wb.x, acc[4]);
    acc[5]  = fmaf(xv, wb.y, acc[5]);
    acc[6]  = fmaf(xv, wb.z, acc[6]);
    acc[7]  = fmaf(xv, wb.w, acc[7]);
    acc[8]  = fmaf(xv, wc.x, acc[8]);
    acc[9]  = fmaf(xv, wc.y, acc[9]);
    acc[10] = fmaf(xv, wc.z, acc[10]);
    acc[11] = fmaf(xv, wc.w, acc[11]);
    acc[12] = fmaf(xv, wd.x, acc[12]);
    acc[13] = fmaf(xv, wd.y, acc[13]);
    acc[14] = fmaf(xv, wd.z, acc[14]);
    acc[15] = fmaf(xv, wd.w, acc[15]);
  }
  __syncthreads();           // all reads of xs done; hb2 may overlay now
#pragma unroll
  for (int m = 0; m < 16; ++m) {
    int c = cg * 16 + m;
    float z = acc[m] + prm[384 + c];
    z = z > 0.f ? z : 0.f;
    xbuf[j * 132 + c] = z * prm[512 + c] + prm[640 + c];  // hb2
  }
  __syncthreads();
  if (tid < 128) {
    int c = tid;
    float mx = xbuf[c];
#pragma unroll
    for (int r = 1; r < NSAMP; ++r) mx = fmaxf(mx, xbuf[r * 132 + c]);
    out_feat[(size_t)(b * NP + s) * C3 + c] = mx;
  }
}

extern "C" void kernel_launch(void* const* d_in, const int* in_sizes, int n_in,
                              void* d_out, int out_size, void* d_ws, size_t ws_size,
                              hipStream_t stream) {
  const float* xyz = (const float*)d_in[0];
  const float* points = (const float*)d_in[1];
  const float* W0 = (const float*)d_in[2];
  const float* b0 = (const float*)d_in[3];
  const float* g0 = (const float*)d_in[4];
  const float* be0 = (const float*)d_in[5];
  const float* W1 = (const float*)d_in[6];
  const float* b1 = (const float*)d_in[7];
  const float* g1 = (const float*)d_in[8];
  const float* be1 = (const float*)d_in[9];
  const float* W2 = (const float*)d_in[10];
  const float* b2 = (const float*)d_in[11];
  const float* g2 = (const float*)d_in[12];
  const float* be2 = (const float*)d_in[13];
  float* out = (float*)d_out;
  unsigned short* fps = (unsigned short*)d_ws;          // 16 KB
  unsigned short* gidx = fps + (size_t)NB * NP;         // 512 KB
  fps_kernel<<<NB, 256, 0, stream>>>(xyz, fps, out);
  ballq_kernel<<<(NB * NP) / 4, 256, 0, stream>>>(xyz, fps, gidx);
  mlp_kernel<<<NB * NP, 256, 0, stream>>>(xyz, points, fps, gidx, W0, b0, g0, be0,
                                          W1, b1, g1, be1, W2, b2, g2, be2,
                                          out + (size_t)NB * NP * 3);
}